// Round 10
// baseline (160.382 us; speedup 1.0000x reference)
//
#include <hip/hip_runtime.h>
#include <math.h>

// Problem constants
#define BB    4
#define CIN   256
#define HH    64
#define WWID  64
#define COUT  256
#define KKS   3
#define K2    9
#define PADV  1
#define HWSZ  4096
#define GROUPS 32
#define CPG   8
#define EPSV  1e-5f
#define ROWB  4608          // K2*CIN * sizeof(f16)
#define NKC   18            // K chunks of 128

typedef __attribute__((ext_vector_type(8))) _Float16 f16x8;
typedef __attribute__((ext_vector_type(2))) _Float16 h2;
typedef __attribute__((ext_vector_type(4))) float f32x4;

#define GLOAD_LDS16(g, l) \
    __builtin_amdgcn_global_load_lds((const __attribute__((address_space(1))) unsigned int*)(g), \
                                     (__attribute__((address_space(3))) unsigned int*)(l), 16, 0, 0)

// physical 16B-chunk position within a 256-B window, row-dependent swizzle
// (verified 0-conflict in R3 on identical geometry)
__device__ __forceinline__ int physchunk(int c, int row) {
    return ((c & 7) ^ (row & 7)) | ((c & 8) ^ ((row & 1) << 3));
}

union U4h { uint4 q; h2 h[4]; };
union U1h { unsigned u; h2 h; };

// ---------------------------------------------------------------------------
// k_pre: grid (129, 8, 4).
//  bx<128 : x NCHW -> NHWC fp16 tile transpose
//  bx==128: weight [Cout][Cin][K2] -> fp16 [co][k2][w2(128ch)][chunk swz]
//           block (128,0,0) zeroes gstat (strided loop covers all)
// ---------------------------------------------------------------------------
__global__ __launch_bounds__(256)
void k_pre(const float* __restrict__ x, unsigned short* __restrict__ xh,
           const float* __restrict__ w, unsigned short* __restrict__ wtb,
           float* __restrict__ gstat) {
    int t = threadIdx.x;
    if (blockIdx.x < 128) {
        __shared__ float tile[32][33];
        int hw0 = blockIdx.x * 32;
        int c0  = blockIdx.y * 32;
        int b   = blockIdx.z;
        int tx = t & 31, ty = t >> 5;
        const float* xp = x + (size_t)b * CIN * HWSZ;
        #pragma unroll
        for (int i = 0; i < 4; i++)
            tile[ty + i * 8][tx] = xp[(c0 + ty + i * 8) * HWSZ + hw0 + tx];
        __syncthreads();
        int j = t >> 3, cq = t & 7;
        union { _Float16 h[4]; uint2 d; } pk;
        #pragma unroll
        for (int k = 0; k < 4; k++) pk.h[k] = (_Float16)tile[cq * 4 + k][j];
        *(uint2*)((char*)xh + ((size_t)b * HWSZ * CIN + (size_t)(hw0 + j) * CIN + c0 + cq * 4) * 2) = pk.d;
    } else {
        if (blockIdx.y == 0 && blockIdx.z == 0)
            for (int i = t; i < BB * GROUPS * 2 + 8; i += 256) gstat[i] = 0.f;
        int idx = (blockIdx.y * 4 + blockIdx.z) * 256 + t;   // [0,8192)
        int co = idx >> 5, c8 = idx & 31;
        int cin0 = c8 * 8;
        int w2 = c8 >> 4, c = c8 & 15;
        int pc = physchunk(c, co);
        for (int k2 = 0; k2 < K2; k2++) {
            union { _Float16 h[8]; uint4 qq; } pk;
            #pragma unroll
            for (int j = 0; j < 8; j++)
                pk.h[j] = (_Float16)w[(co * CIN + cin0 + j) * K2 + k2];
            int phys = co * ROWB + k2 * 512 + w2 * 256 + pc * 16;
            *(uint4*)((char*)wtb + phys) = pk.qq;
        }
    }
}

// ---------------------------------------------------------------------------
// k_conv: fused-sampling implicit GEMM, fp16 path. 512 blocks x 256 thr,
// 2 blocks/CU. Per block: M=128 x N=64 px strip, K=2304 in 18 x BK=128.
// K-loop: [glds A(kc) + pk_fma pack Bs(kc)] barrier
//         [issue reg-gathers(kc+1)] [MFMA(kc) x32/wave] barrier.
// Sampling math in packed fp16 (v_pk_fma_f16): no unpack, no cvt, no repack.
// ---------------------------------------------------------------------------
__global__ __launch_bounds__(256)
void k_conv(const unsigned short* __restrict__ wtb, const unsigned short* __restrict__ xh,
            const float* __restrict__ offset, const float* __restrict__ mask,
            const float* __restrict__ bias, float* __restrict__ out,
            float* __restrict__ gstat) {
    __shared__ unsigned short As[128 * 128];  // 32 KB
    __shared__ unsigned short Bs[64 * 128];   // 16 KB
    __shared__ int      cidx[64 * K2 * 4];    // 9 KB
    __shared__ unsigned cwgt[64 * K2 * 4];    // 9 KB (half2-broadcast weights)
    __shared__ float gs[16], gss[16];

    // block decode: XCD k = bid&7 owns strips k*32..k*32+31, both m-halves
    int lid = blockIdx.x;
    int j8  = lid >> 3;
    int mt  = j8 & 1;
    int strip = (lid & 7) * 32 + (j8 >> 1);   // 0..255
    int b = strip >> 6;
    int hwbase = (strip & 63) * 64;
    int m0 = mt * 128;

    int t = threadIdx.x, w = t >> 6, l = t & 63;
    int r16 = l & 15, half = l >> 4;
    int wm = w & 1, wn = w >> 1;

    if (t < 16) { gs[t] = 0.f; gss[t] = 0.f; }

    // ---- corner prep: 576 (px,k2) pairs; weights packed half2
    for (int i = t; i < 64 * K2; i += 256) {
        int px = i / K2, k2 = i - px * K2;
        int hw = hwbase + px;
        int ho = hw >> 6, wo = hw & 63;
        int ky = k2 / KKS, kx = k2 - ky * KKS;
        float dy = offset[((b * (2 * K2) + k2 * 2 + 0) * HWSZ) + hw];
        float dx = offset[((b * (2 * K2) + k2 * 2 + 1) * HWSZ) + hw];
        float m  = mask[(b * K2 + k2) * HWSZ + hw];
        float y  = (float)(ky + ho - PADV) + dy;
        float xc = (float)(kx + wo - PADV) + dx;
        float y0f = floorf(y), x0f = floorf(xc);
        float fy = y - y0f, fx = xc - x0f;
        int y0 = (int)y0f, x0 = (int)x0f;
        int   yy[2] = { y0, y0 + 1 };
        int   xx[2] = { x0, x0 + 1 };
        float wy[2] = { 1.f - fy, fy };
        float wx[2] = { 1.f - fx, fx };
        #pragma unroll
        for (int ii = 0; ii < 2; ii++)
            #pragma unroll
            for (int jj = 0; jj < 2; jj++) {
                int yi = yy[ii], xi = xx[jj];
                bool valid = (yi >= 0) && (yi < HH) && (xi >= 0) && (xi < WWID);
                int yc  = min(max(yi, 0), HH - 1);
                int xcc = min(max(xi, 0), WWID - 1);
                cidx[i * 4 + ii * 2 + jj] = yc * WWID + xcc;
                float wv = valid ? (wy[ii] * wx[jj] * m) : 0.f;
                U1h cw; cw.h = h2{(_Float16)wv, (_Float16)wv};
                cwgt[i * 4 + ii * 2 + jj] = cw.u;
            }
    }

    // ---- A staging: 2048 x 16B chunks per kc, 8/thread; +256 B per kc
    const char* ag[8]; unsigned short* lA[8];
    #pragma unroll
    for (int i = 0; i < 8; i++) {
        int o = (w * 8 + i) * 64 + l;
        ag[i] = (const char*)wtb + (size_t)(m0 + (o >> 4)) * ROWB + (o & 15) * 16;
        lA[i] = (unsigned short*)As + (w * 8 + i) * 512;
    }

    // ---- sampling mapping: spx = t>>2 (64 px), sq = t&3 (64B quarter of row)
    int spx = t >> 2, sq = t & 3;
    const char* xb = (const char*)xh + (size_t)b * HWSZ * CIN * 2;
    int bq[4];
    #pragma unroll
    for (int j = 0; j < 4; j++)
        bq[j] = spx * 128 + physchunk(sq * 4 + j, spx) * 8;   // Bs short-offsets

    f32x4 acc[4][2];
    #pragma unroll
    for (int mi = 0; mi < 4; mi++)
        #pragma unroll
        for (int ni = 0; ni < 2; ni++) acc[mi][ni] = (f32x4)0.f;

    __syncthreads();   // coef + gs ready

    // prologue gathers for kc=0 (k2=0, halfsel=0)
    uint4 g[4][4]; h2 gw[4];
    {
        int cb = (spx * K2) * 4;
        #pragma unroll
        for (int c = 0; c < 4; c++) {
            U1h cw; cw.u = cwgt[cb + c]; gw[c] = cw.h;
            const char* p = xb + (size_t)cidx[cb + c] * 512 + sq * 64;
            #pragma unroll
            for (int j = 0; j < 4; j++) g[c][j] = *(const uint4*)(p + j * 16);
        }
    }

    for (int kc = 0; kc < NKC; kc++) {
        // A: async global->LDS (DMA overlaps the pack VALU below)
        #pragma unroll
        for (int i = 0; i < 8; i++) { GLOAD_LDS16(ag[i], lA[i]); ag[i] += 256; }

        // pack: packed-f16 bilinear -> Bs
        #pragma unroll
        for (int j = 0; j < 4; j++) {
            h2 a0 = h2{0, 0}, a1 = h2{0, 0}, a2 = h2{0, 0}, a3 = h2{0, 0};
            #pragma unroll
            for (int c = 0; c < 4; c++) {
                U4h xv; xv.q = g[c][j];
                a0 = gw[c] * xv.h[0] + a0;
                a1 = gw[c] * xv.h[1] + a1;
                a2 = gw[c] * xv.h[2] + a2;
                a3 = gw[c] * xv.h[3] + a3;
            }
            U4h o; o.h[0] = a0; o.h[1] = a1; o.h[2] = a2; o.h[3] = a3;
            *(uint4*)&Bs[bq[j]] = o.q;
        }
        __syncthreads();   // As staged (vmcnt) + Bs written (lgkm)

        // prefetch gathers for kc+1 (register dest — fly during MFMA)
        if (kc < NKC - 1) {
            int kn = kc + 1;
            int k2n = kn >> 1, hs = kn & 1;
            int cb = (spx * K2 + k2n) * 4;
            #pragma unroll
            for (int c = 0; c < 4; c++) {
                U1h cw; cw.u = cwgt[cb + c]; gw[c] = cw.h;
                const char* p = xb + (size_t)cidx[cb + c] * 512 + hs * 256 + sq * 64;
                #pragma unroll
                for (int j = 0; j < 4; j++) g[c][j] = *(const uint4*)(p + j * 16);
            }
        }

        // MFMA(kc): 4 ks x 8 = 32 per wave
        #pragma unroll
        for (int ks = 0; ks < 4; ks++) {
            int ks4 = ks * 4 + half;
            int up  = physchunk(ks4, r16) * 8;
            f16x8 af[4], bv[2];
            #pragma unroll
            for (int mi = 0; mi < 4; mi++)
                af[mi] = *(const f16x8*)&As[(wm * 64 + mi * 16 + r16) * 128 + up];
            #pragma unroll
            for (int ni = 0; ni < 2; ni++)
                bv[ni] = *(const f16x8*)&Bs[(wn * 32 + ni * 16 + r16) * 128 + up];
            #pragma unroll
            for (int mi = 0; mi < 4; mi++)
                #pragma unroll
                for (int ni = 0; ni < 2; ni++)
                    acc[mi][ni] = __builtin_amdgcn_mfma_f32_16x16x32_f16(
                        af[mi], bv[ni], acc[mi][ni], 0, 0, 0);
        }
        __syncthreads();
    }

    // epilogue: bias + store + GN partials (C/D: col=lane&15 -> n, row=half*4+reg -> m)
    float s4[4] = {0,0,0,0}, ss4[4] = {0,0,0,0};
    #pragma unroll
    for (int mi = 0; mi < 4; mi++) {
        #pragma unroll
        for (int r = 0; r < 4; r++) {
            int co = m0 + wm * 64 + mi * 16 + half * 4 + r;
            float bs = bias[co];
            float* orow = out + ((size_t)(b * COUT + co)) * HWSZ;
            #pragma unroll
            for (int ni = 0; ni < 2; ni++) {
                int n = hwbase + wn * 32 + ni * 16 + r16;
                float v = acc[mi][ni][r] + bs;
                orow[n] = v;
                s4[mi] += v; ss4[mi] += v * v;
            }
        }
    }
    int gb = half >> 1;
    #pragma unroll
    for (int mi = 0; mi < 4; mi++) {
        atomicAdd(&gs [wm * 8 + mi * 2 + gb], s4[mi]);
        atomicAdd(&gss[wm * 8 + mi * 2 + gb], ss4[mi]);
    }
    __syncthreads();
    if (t < 16) {
        int gidx = (m0 >> 3) + t;
        atomicAdd(&gstat[(b * GROUPS + gidx) * 2 + 0], gs[t]);
        atomicAdd(&gstat[(b * GROUPS + gidx) * 2 + 1], gss[t]);
    }
}

// ---------------------------------------------------------------------------
// finalize: normalize + affine + ReLU in place (float4)
// ---------------------------------------------------------------------------
__global__ __launch_bounds__(256)
void k_gnfinal(float* __restrict__ out, const float* __restrict__ gstat,
               const float* __restrict__ gamma, const float* __restrict__ beta) {
    int i4 = blockIdx.x * 256 + threadIdx.x;
    int e  = i4 * 4;
    int c  = (e >> 12) & 255;
    int b  = e >> 20;
    int g  = c >> 3;
    float s  = gstat[((b * GROUPS) + g) * 2 + 0];
    float ss = gstat[((b * GROUPS) + g) * 2 + 1];
    const float inv = 1.f / (float)(CPG * HWSZ);
    float mu  = s * inv;
    float var = ss * inv - mu * mu;
    float rstd = rsqrtf(var + EPSV);
    float ga = gamma[c] * rstd;
    float be = beta[c] - mu * ga;
    float4 v = ((float4*)out)[i4];
    v.x = fmaxf(v.x * ga + be, 0.f);
    v.y = fmaxf(v.y * ga + be, 0.f);
    v.z = fmaxf(v.z * ga + be, 0.f);
    v.w = fmaxf(v.w * ga + be, 0.f);
    ((float4*)out)[i4] = v;
}

// ---------------------------------------------------------------------------
extern "C" void kernel_launch(void* const* d_in, const int* in_sizes, int n_in,
                              void* d_out, int out_size, void* d_ws, size_t ws_size,
                              hipStream_t stream) {
    const float* x      = (const float*)d_in[0];
    const float* offset = (const float*)d_in[1];
    const float* mask   = (const float*)d_in[2];
    const float* weight = (const float*)d_in[3];
    const float* bias   = (const float*)d_in[4];
    const float* gamma  = (const float*)d_in[5];
    const float* beta   = (const float*)d_in[6];
    float* out = (float*)d_out;

    // workspace (~10 MB)
    unsigned short* xh    = (unsigned short*)d_ws;              // 4,194,304 us (8.4 MB)
    unsigned short* wtb   = xh + (size_t)4194304;               //   589,824 us (1.2 MB)
    float*          gstat = (float*)(wtb + (size_t)589824);     // 264 f

    k_pre<<<dim3(129, 8, 4), 256, 0, stream>>>(x, xh, weight, wtb, gstat);
    k_conv<<<512, 256, 0, stream>>>(wtb, xh, offset, mask, bias, out, gstat);
    k_gnfinal<<<(size_t)BB * COUT * HWSZ / 1024, 256, 0, stream>>>(out, gstat, gamma, beta);
}

// Round 11
// 152.686 us; speedup vs baseline: 1.0504x; 1.0504x over previous
//
#include <hip/hip_runtime.h>
#include <math.h>

// Problem constants
#define BB    4
#define CIN   256
#define HH    64
#define WWID  64
#define COUT  256
#define KKS   3
#define K2    9
#define PADV  1
#define HWSZ  4096
#define GROUPS 32
#define CPG   8
#define EPSV  1e-5f
#define ROWB  4608          // K2*CIN * sizeof(f16)
#define NKC   36            // K chunks of 64

typedef __attribute__((ext_vector_type(8))) _Float16 f16x8;
typedef __attribute__((ext_vector_type(2))) _Float16 h2;
typedef __attribute__((ext_vector_type(4))) float f32x4;

#define GLOAD_LDS16(g, l) \
    __builtin_amdgcn_global_load_lds((const __attribute__((address_space(1))) unsigned int*)(g), \
                                     (__attribute__((address_space(3))) unsigned int*)(l), 16, 0, 0)

union U4h { uint4 q; h2 h[4]; };
union U1h { unsigned u; h2 h; };

// ---------------------------------------------------------------------------
// k_pre: grid (129, 8, 4).
//  bx<128 : x NCHW -> NHWC fp16 tile transpose
//  bx==128: weight [Cout][Cin][K2] -> fp16 [co][k2][q(64ch)][chunk c^(co&7)]
//           block (128,0,0) zeroes gstat (strided loop covers all)
// ---------------------------------------------------------------------------
__global__ __launch_bounds__(256)
void k_pre(const float* __restrict__ x, unsigned short* __restrict__ xh,
           const float* __restrict__ w, unsigned short* __restrict__ wtb,
           float* __restrict__ gstat) {
    int t = threadIdx.x;
    if (blockIdx.x < 128) {
        __shared__ float tile[32][33];
        int hw0 = blockIdx.x * 32;
        int c0  = blockIdx.y * 32;
        int b   = blockIdx.z;
        int tx = t & 31, ty = t >> 5;
        const float* xp = x + (size_t)b * CIN * HWSZ;
        #pragma unroll
        for (int i = 0; i < 4; i++)
            tile[ty + i * 8][tx] = xp[(c0 + ty + i * 8) * HWSZ + hw0 + tx];
        __syncthreads();
        int j = t >> 3, cq = t & 7;
        union { _Float16 h[4]; uint2 d; } pk;
        #pragma unroll
        for (int k = 0; k < 4; k++) pk.h[k] = (_Float16)tile[cq * 4 + k][j];
        *(uint2*)((char*)xh + ((size_t)b * HWSZ * CIN + (size_t)(hw0 + j) * CIN + c0 + cq * 4) * 2) = pk.d;
    } else {
        if (blockIdx.y == 0 && blockIdx.z == 0)
            for (int i = t; i < BB * GROUPS * 2 + 8; i += 256) gstat[i] = 0.f;
        int idx = (blockIdx.y * 4 + blockIdx.z) * 256 + t;   // [0,8192)
        int co = idx >> 5, c8 = idx & 31;
        int cin0 = c8 * 8;
        int q = c8 >> 3, c = c8 & 7;
        int pc = c ^ (co & 7);
        for (int k2 = 0; k2 < K2; k2++) {
            union { _Float16 h[8]; uint4 qq; } pk;
            #pragma unroll
            for (int j = 0; j < 8; j++)
                pk.h[j] = (_Float16)w[(co * CIN + cin0 + j) * K2 + k2];
            int phys = co * ROWB + k2 * 512 + q * 128 + pc * 16;
            *(uint4*)((char*)wtb + phys) = pk.qq;
        }
    }
}

// ---------------------------------------------------------------------------
// k_conv: fused-sampling implicit GEMM, fp16. 512 blocks x 256 thr,
// 3 blocks/CU (43.5 KB LDS — R8 geometry, measured 0 conflicts).
// Per block: M=128 x N=64 px strip, K=2304 in 36 x BK=64.
// K-loop (m97 pattern): [glds A(kc) + pk_fma pack Bs(kc)] barrier
//                       [issue reg-gathers(kc+1)] [MFMA(kc) x16/wave] barrier.
// ---------------------------------------------------------------------------
__global__ __launch_bounds__(256)
void k_conv(const unsigned short* __restrict__ wtb, const unsigned short* __restrict__ xh,
            const float* __restrict__ offset, const float* __restrict__ mask,
            const float* __restrict__ bias, float* __restrict__ out,
            float* __restrict__ gstat) {
    __shared__ unsigned short As[128 * 64];   // 16 KB
    __shared__ unsigned short Bs[64 * 64];    // 8 KB
    __shared__ int      cidx[64 * K2 * 4];    // 9 KB
    __shared__ unsigned cwgt[64 * K2 * 4];    // 9 KB (half2-broadcast weights)
    __shared__ float gs[16], gss[16];

    // block decode: XCD k = bid&7 owns strips k*32..k*32+31, both m-halves
    int lid = blockIdx.x;
    int j8  = lid >> 3;
    int mt  = j8 & 1;
    int strip = (lid & 7) * 32 + (j8 >> 1);   // 0..255
    int b = strip >> 6;
    int hwbase = (strip & 63) * 64;
    int m0 = mt * 128;

    int t = threadIdx.x, w = t >> 6, l = t & 63;
    int r16 = l & 15, half = l >> 4;
    int wm = w & 1, wn = w >> 1;
    int skey = r16 & 7;

    if (t < 16) { gs[t] = 0.f; gss[t] = 0.f; }

    // ---- corner prep: 576 (px,k2) pairs; weights packed half2
    for (int i = t; i < 64 * K2; i += 256) {
        int px = i / K2, k2 = i - px * K2;
        int hw = hwbase + px;
        int ho = hw >> 6, wo = hw & 63;
        int ky = k2 / KKS, kx = k2 - ky * KKS;
        float dy = offset[((b * (2 * K2) + k2 * 2 + 0) * HWSZ) + hw];
        float dx = offset[((b * (2 * K2) + k2 * 2 + 1) * HWSZ) + hw];
        float m  = mask[(b * K2 + k2) * HWSZ + hw];
        float y  = (float)(ky + ho - PADV) + dy;
        float xc = (float)(kx + wo - PADV) + dx;
        float y0f = floorf(y), x0f = floorf(xc);
        float fy = y - y0f, fx = xc - x0f;
        int y0 = (int)y0f, x0 = (int)x0f;
        int   yy[2] = { y0, y0 + 1 };
        int   xx[2] = { x0, x0 + 1 };
        float wy[2] = { 1.f - fy, fy };
        float wx[2] = { 1.f - fx, fx };
        #pragma unroll
        for (int ii = 0; ii < 2; ii++)
            #pragma unroll
            for (int jj = 0; jj < 2; jj++) {
                int yi = yy[ii], xi = xx[jj];
                bool valid = (yi >= 0) && (yi < HH) && (xi >= 0) && (xi < WWID);
                int yc  = min(max(yi, 0), HH - 1);
                int xcc = min(max(xi, 0), WWID - 1);
                cidx[i * 4 + ii * 2 + jj] = yc * WWID + xcc;
                float wv = valid ? (wy[ii] * wx[jj] * m) : 0.f;
                U1h cw; cw.h = h2{(_Float16)wv, (_Float16)wv};
                cwgt[i * 4 + ii * 2 + jj] = cw.u;
            }
    }

    // ---- A staging: 1024 x 16B chunks per kc, 4/thread; +128 B per kc
    const char* ag[4]; unsigned short* lA[4];
    #pragma unroll
    for (int i = 0; i < 4; i++) {
        int o = i * 256 + t;
        ag[i] = (const char*)wtb + (size_t)(m0 + (o >> 3)) * ROWB + (o & 7) * 16;
        lA[i] = (unsigned short*)As + o * 8;
    }

    // ---- sampling mapping: 2 items/thread: px0 = t>>3 (+32), sc = t&7
    int sc  = t & 7;
    int px0 = t >> 3;
    const char* xb = (const char*)xh + (size_t)b * HWSZ * CIN * 2;
    int bofs0 = px0 * 64 + (sc ^ (px0 & 7)) * 8;
    int px1 = px0 + 32;
    int bofs1 = px1 * 64 + (sc ^ (px1 & 7)) * 8;

    f32x4 acc[4][2];
    #pragma unroll
    for (int mi = 0; mi < 4; mi++)
        #pragma unroll
        for (int ni = 0; ni < 2; ni++) acc[mi][ni] = (f32x4)0.f;

    __syncthreads();   // coef + gs ready

    // prologue gathers for kc=0 (k2=0, q=0)
    uint4 g[2][4]; h2 gw[2][4];
    #pragma unroll
    for (int it = 0; it < 2; it++) {
        int cb = ((it ? px1 : px0) * K2) * 4;
        #pragma unroll
        for (int c = 0; c < 4; c++) {
            U1h cw; cw.u = cwgt[cb + c]; gw[it][c] = cw.h;
            g[it][c] = *(const uint4*)(xb + (size_t)cidx[cb + c] * 512 + sc * 16);
        }
    }

    for (int kc = 0; kc < NKC; kc++) {
        // A: async global->LDS (DMA overlaps pack VALU below)
        #pragma unroll
        for (int i = 0; i < 4; i++) { GLOAD_LDS16(ag[i], lA[i]); ag[i] += 128; }

        // pack: packed-f16 bilinear -> Bs (4 pk_fma per corner per px)
        #pragma unroll
        for (int it = 0; it < 2; it++) {
            h2 a0 = h2{0, 0}, a1 = h2{0, 0}, a2 = h2{0, 0}, a3 = h2{0, 0};
            #pragma unroll
            for (int c = 0; c < 4; c++) {
                U4h xv; xv.q = g[it][c];
                h2 wv = gw[it][c];
                a0 = wv * xv.h[0] + a0;
                a1 = wv * xv.h[1] + a1;
                a2 = wv * xv.h[2] + a2;
                a3 = wv * xv.h[3] + a3;
            }
            U4h o; o.h[0] = a0; o.h[1] = a1; o.h[2] = a2; o.h[3] = a3;
            *(uint4*)&Bs[it ? bofs1 : bofs0] = o.q;
        }
        __syncthreads();   // As staged (vmcnt) + Bs written (lgkm)

        // prefetch gathers for kc+1 (register dest — fly during MFMA,
        // drained at next barrier which is exactly when they're consumed)
        if (kc < NKC - 1) {
            int kn = kc + 1;
            int k2n = kn >> 2, qn = kn & 3;
            #pragma unroll
            for (int it = 0; it < 2; it++) {
                int cb = ((it ? px1 : px0) * K2 + k2n) * 4;
                #pragma unroll
                for (int c = 0; c < 4; c++) {
                    U1h cw; cw.u = cwgt[cb + c]; gw[it][c] = cw.h;
                    g[it][c] = *(const uint4*)(xb + (size_t)cidx[cb + c] * 512 + qn * 128 + sc * 16);
                }
            }
        }

        // MFMA(kc): 2 ks x 8 = 16 per wave
        #pragma unroll
        for (int ks = 0; ks < 2; ks++) {
            int up = ((ks * 4 + half) ^ skey) * 8;
            f16x8 af[4], bv[2];
            #pragma unroll
            for (int mi = 0; mi < 4; mi++)
                af[mi] = *(const f16x8*)&As[(wm * 64 + mi * 16 + r16) * 64 + up];
            #pragma unroll
            for (int ni = 0; ni < 2; ni++)
                bv[ni] = *(const f16x8*)&Bs[(wn * 32 + ni * 16 + r16) * 64 + up];
            #pragma unroll
            for (int mi = 0; mi < 4; mi++)
                #pragma unroll
                for (int ni = 0; ni < 2; ni++)
                    acc[mi][ni] = __builtin_amdgcn_mfma_f32_16x16x32_f16(
                        af[mi], bv[ni], acc[mi][ni], 0, 0, 0);
        }
        __syncthreads();
    }

    // epilogue: bias + store + GN partials (C/D: col=lane&15 -> n, row=half*4+reg -> m)
    float s4[4] = {0,0,0,0}, ss4[4] = {0,0,0,0};
    #pragma unroll
    for (int mi = 0; mi < 4; mi++) {
        #pragma unroll
        for (int r = 0; r < 4; r++) {
            int co = m0 + wm * 64 + mi * 16 + half * 4 + r;
            float bs = bias[co];
            float* orow = out + ((size_t)(b * COUT + co)) * HWSZ;
            #pragma unroll
            for (int ni = 0; ni < 2; ni++) {
                int n = hwbase + wn * 32 + ni * 16 + r16;
                float v = acc[mi][ni][r] + bs;
                orow[n] = v;
                s4[mi] += v; ss4[mi] += v * v;
            }
        }
    }
    int gb = half >> 1;
    #pragma unroll
    for (int mi = 0; mi < 4; mi++) {
        atomicAdd(&gs [wm * 8 + mi * 2 + gb], s4[mi]);
        atomicAdd(&gss[wm * 8 + mi * 2 + gb], ss4[mi]);
    }
    __syncthreads();
    if (t < 16) {
        int gidx = (m0 >> 3) + t;
        atomicAdd(&gstat[(b * GROUPS + gidx) * 2 + 0], gs[t]);
        atomicAdd(&gstat[(b * GROUPS + gidx) * 2 + 1], gss[t]);
    }
}

// ---------------------------------------------------------------------------
// finalize: normalize + affine + ReLU in place (float4)
// ---------------------------------------------------------------------------
__global__ __launch_bounds__(256)
void k_gnfinal(float* __restrict__ out, const float* __restrict__ gstat,
               const float* __restrict__ gamma, const float* __restrict__ beta) {
    int i4 = blockIdx.x * 256 + threadIdx.x;
    int e  = i4 * 4;
    int c  = (e >> 12) & 255;
    int b  = e >> 20;
    int g  = c >> 3;
    float s  = gstat[((b * GROUPS) + g) * 2 + 0];
    float ss = gstat[((b * GROUPS) + g) * 2 + 1];
    const float inv = 1.f / (float)(CPG * HWSZ);
    float mu  = s * inv;
    float var = ss * inv - mu * mu;
    float rstd = rsqrtf(var + EPSV);
    float ga = gamma[c] * rstd;
    float be = beta[c] - mu * ga;
    float4 v = ((float4*)out)[i4];
    v.x = fmaxf(v.x * ga + be, 0.f);
    v.y = fmaxf(v.y * ga + be, 0.f);
    v.z = fmaxf(v.z * ga + be, 0.f);
    v.w = fmaxf(v.w * ga + be, 0.f);
    ((float4*)out)[i4] = v;
}

// ---------------------------------------------------------------------------
extern "C" void kernel_launch(void* const* d_in, const int* in_sizes, int n_in,
                              void* d_out, int out_size, void* d_ws, size_t ws_size,
                              hipStream_t stream) {
    const float* x      = (const float*)d_in[0];
    const float* offset = (const float*)d_in[1];
    const float* mask   = (const float*)d_in[2];
    const float* weight = (const float*)d_in[3];
    const float* bias   = (const float*)d_in[4];
    const float* gamma  = (const float*)d_in[5];
    const float* beta   = (const float*)d_in[6];
    float* out = (float*)d_out;

    // workspace (~10 MB)
    unsigned short* xh    = (unsigned short*)d_ws;              // 4,194,304 us (8.4 MB)
    unsigned short* wtb   = xh + (size_t)4194304;               //   589,824 us (1.2 MB)
    float*          gstat = (float*)(wtb + (size_t)589824);     // 264 f

    k_pre<<<dim3(129, 8, 4), 256, 0, stream>>>(x, xh, weight, wtb, gstat);
    k_conv<<<512, 256, 0, stream>>>(wtb, xh, offset, mask, bias, out, gstat);
    k_gnfinal<<<(size_t)BB * COUT * HWSZ / 1024, 256, 0, stream>>>(out, gstat, gamma, beta);
}